// Round 2
// baseline (954.674 us; speedup 1.0000x reference)
//
#include <hip/hip_runtime.h>
#include <hip/hip_bf16.h>
#include <math.h>

// ---------------------------------------------------------------------------
// MHLA: out, l_kv = MLA(x, cache, W_kv, W_q, W_lq, W_o)
//   l_kv_new = x @ W_kv                      (8192x2048)·(2048x512)
//   lq       = x @ (W_q @ W_lq)              (folded: W_comb is 2048x512)
//   l_kv     = concat(cache, l_kv_new)       (2, 8192, 512)
//   ctx      = softmax(lq·l_kv^T/sqrt(512))·l_kv   (flash, T=8192)
//   out      = ctx @ W_o                     (8192x512)·(512x2048)
// All matmuls on fp16 MFMA (f32 accum). d_out's "out" region doubles as
// scratch for buffers that die before the final GEMM rewrites it.
// ---------------------------------------------------------------------------

typedef _Float16 f16x8 __attribute__((ext_vector_type(8)));
typedef _Float16 f16x4 __attribute__((ext_vector_type(4)));
typedef float    f32x4 __attribute__((ext_vector_type(4)));

// ---------------------------- elementwise converts -------------------------

__global__ __launch_bounds__(256) void k_cvt(const float* __restrict__ in,
                                             _Float16* __restrict__ out, int n4) {
  int i = blockIdx.x * blockDim.x + threadIdx.x;
  int st = gridDim.x * blockDim.x;
  for (; i < n4; i += st) {
    f32x4 v = reinterpret_cast<const f32x4*>(in)[i];
    reinterpret_cast<f16x4*>(out)[i] = __builtin_convertvector(v, f16x4);
  }
}

// cache (2,4096,512) -> l_kv f32 out rows [b*8192 + t] and fp16 copy
__global__ __launch_bounds__(256) void k_cache(const float* __restrict__ cache,
                                               float* __restrict__ lkv_f32,
                                               _Float16* __restrict__ lkv16, int n4) {
  int i = blockIdx.x * blockDim.x + threadIdx.x;
  int st = gridDim.x * blockDim.x;
  for (; i < n4; i += st) {
    f32x4 v = reinterpret_cast<const f32x4*>(cache)[i];
    int e = i << 2;
    int b = e >> 21;                 // 4096*512 = 2^21
    int dst = e + (b << 21);         // batch stride in l_kv is 2^22
    *reinterpret_cast<f32x4*>(lkv_f32 + dst) = v;
    *reinterpret_cast<f16x4*>(lkv16 + dst) = __builtin_convertvector(v, f16x4);
  }
}

// transpose+convert: in f32 (R x C) -> out fp16 (C x R)
__global__ __launch_bounds__(256) void k_tc(const float* __restrict__ in,
                                            _Float16* __restrict__ out, int R, int C) {
  __shared__ float t[32][33];
  const int c0 = blockIdx.x << 5, r0 = blockIdx.y << 5;
  const int tid = threadIdx.x;
  {
    int r = tid >> 3, c4 = (tid & 7) << 2;
    f32x4 v = *reinterpret_cast<const f32x4*>(&in[(long)(r0 + r) * C + c0 + c4]);
    t[r][c4] = v[0]; t[r][c4 + 1] = v[1]; t[r][c4 + 2] = v[2]; t[r][c4 + 3] = v[3];
  }
  __syncthreads();
  {
    int c = tid >> 3, r4 = (tid & 7) << 2;
    f16x4 o = {(_Float16)t[r4][c], (_Float16)t[r4 + 1][c],
               (_Float16)t[r4 + 2][c], (_Float16)t[r4 + 3][c]};
    *reinterpret_cast<f16x4*>(&out[(long)(c0 + c) * R + r0 + r4]) = o;
  }
}

// transpose fp16: in (R x C) -> out (C x R)
__global__ __launch_bounds__(256) void k_tb(const _Float16* __restrict__ in,
                                            _Float16* __restrict__ out, int R, int C) {
  __shared__ _Float16 t[32][36];
  const int c0 = blockIdx.x << 5, r0 = blockIdx.y << 5;
  const int tid = threadIdx.x;
  {
    int r = tid >> 3, c4 = (tid & 7) << 2;
    f16x4 v = *reinterpret_cast<const f16x4*>(&in[(long)(r0 + r) * C + c0 + c4]);
    t[r][c4] = v[0]; t[r][c4 + 1] = v[1]; t[r][c4 + 2] = v[2]; t[r][c4 + 3] = v[3];
  }
  __syncthreads();
  {
    int c = tid >> 3, r4 = (tid & 7) << 2;
    f16x4 o = {t[r4][c], t[r4 + 1][c], t[r4 + 2][c], t[r4 + 3][c]};
    *reinterpret_cast<f16x4*>(&out[(long)(c0 + c) * R + r0 + r4]) = o;
  }
}

// ---------------------------------- GEMM -----------------------------------
// C[M,N] = A[M,K] @ B^T[N,K]   (A row-major k-contig, B passed transposed)
// 128x128 tile, BK=64, 4 waves (each 64x64 = 4x4 frags of 16x16), fp16 MFMA.
// Reg-staged global->LDS, XOR-swizzled LDS ((row&7) on 16B slots).
// CMODE: 0 = f32 C ; 1 = fp16 C ; 2 = f32 + fp16 C with l_kv row remap
//        (row r -> b*8192 + 4096 + s, N must be 512).
template <int CMODE>
__global__ __launch_bounds__(256) void k_gemm(const _Float16* __restrict__ A,
                                              const _Float16* __restrict__ B,
                                              float* __restrict__ Cf,
                                              _Float16* __restrict__ Ch,
                                              int M, int N, int K) {
  __shared__ alignas(16) _Float16 As[128 * 64];
  __shared__ alignas(16) _Float16 Bs[128 * 64];
  const int tid = threadIdx.x;
  const int lane = tid & 63;
  const int w = tid >> 6;
  const int wr = ((w >> 1) & 1) << 6, wc = (w & 1) << 6;
  const int bm = blockIdx.x << 7, bn = blockIdx.y << 7;
  const int g = lane >> 4, ln15 = lane & 15;

  f32x4 acc[4][4] = {};

  const int srowl = lane >> 3;        // row within 8-row chunk
  const int skcol = (lane & 7) << 3;  // k elem offset (0..56)
  // swizzled LDS write index for staging (16B-slot XOR with row&7)
  const int wofs = (srowl << 6) + (((lane & 7) ^ srowl) << 3);

  f16x8 ra[4], rb[4];
  auto loadregs = [&](int k0) {
#pragma unroll
    for (int i = 0; i < 4; ++i) {
      int ch = (w << 2) + i;
      int row = (ch << 3) + srowl;
      ra[i] = *reinterpret_cast<const f16x8*>(&A[(long)(bm + row) * K + k0 + skcol]);
      rb[i] = *reinterpret_cast<const f16x8*>(&B[(long)(bn + row) * K + k0 + skcol]);
    }
  };
  loadregs(0);
  const int nk = K >> 6;
  for (int kt = 0; kt < nk; ++kt) {
    __syncthreads();  // previous iter's LDS reads done
#pragma unroll
    for (int i = 0; i < 4; ++i) {
      int ch = (w << 2) + i;
      *reinterpret_cast<f16x8*>(&As[(ch << 9) + wofs]) = ra[i];
      *reinterpret_cast<f16x8*>(&Bs[(ch << 9) + wofs]) = rb[i];
    }
    __syncthreads();  // staging visible
    if (kt + 1 < nk) loadregs((kt + 1) << 6);
#pragma unroll
    for (int ks = 0; ks < 2; ++ks) {
      f16x8 af[4], bf[4];
#pragma unroll
      for (int i = 0; i < 4; ++i) {
        const int arow = wr + (i << 4) + ln15;
        const int brow = wc + (i << 4) + ln15;
        const int inner = (((ks << 5) + (g << 3)) ^ ((ln15 & 7) << 3));
        af[i] = *reinterpret_cast<const f16x8*>(&As[arow * 64 + inner]);
        bf[i] = *reinterpret_cast<const f16x8*>(&Bs[brow * 64 + inner]);
      }
#pragma unroll
      for (int i = 0; i < 4; ++i)
#pragma unroll
        for (int j = 0; j < 4; ++j)
          acc[i][j] = __builtin_amdgcn_mfma_f32_16x16x32_f16(af[i], bf[j], acc[i][j], 0, 0, 0);
    }
  }
  // epilogue: D frag -> (row = 4*(lane>>4)+r, col = lane&15)
#pragma unroll
  for (int i = 0; i < 4; ++i) {
    const int row = bm + wr + (i << 4) + (g << 2);
#pragma unroll
    for (int j = 0; j < 4; ++j) {
      const int col = bn + wc + (j << 4) + ln15;
#pragma unroll
      for (int r = 0; r < 4; ++r) {
        float v = acc[i][j][r];
        long orow = row + r;
        if constexpr (CMODE == 2) {
          long m2 = ((orow >> 12) << 13) + 4096 + (orow & 4095);
          Cf[m2 * 512 + col] = v;
          Ch[m2 * 512 + col] = (_Float16)v;
        } else if constexpr (CMODE == 1) {
          Ch[orow * N + col] = (_Float16)v;
        } else {
          Cf[orow * N + col] = v;
        }
      }
    }
  }
}

// ------------------------------- attention ---------------------------------
// Per block: 32 Q rows of batch b, flash loop over T=8192 in tiles of 32.
// 4 waves: each computes one 16x16 quarter of S, then owns 128 ctx columns.
__global__ __launch_bounds__(256) void k_attn(const _Float16* __restrict__ lq,    // (8192,512)
                                              const _Float16* __restrict__ lkv,   // (16384,512)
                                              const _Float16* __restrict__ lkvT,  // (512,16384)
                                              _Float16* __restrict__ ctx) {       // (8192,512)
  __shared__ alignas(16) _Float16 lq_s[32 * 512];
  __shared__ alignas(16) _Float16 vt_s[512 * 32];
  __shared__ alignas(16) float S_s[32 * 32];
  __shared__ alignas(16) _Float16 P_s[32 * 64];  // 32x32 used, 64-row pitch for swizzle
  __shared__ float m_s[32], l_s[32], corr_s[32];

  const int tid = threadIdx.x, lane = tid & 63, w = tid >> 6;
  const int b = blockIdx.y;
  const long qrow = (long)b * 4096 + (blockIdx.x << 5);
  const int g = lane >> 4, ln15 = lane & 15;

  // stage lq tile (row = 1KB; swizzle 16B slots with row&7)
#pragma unroll
  for (int i = 0; i < 8; ++i) {
    int c = (w << 3) + i;
    f16x8 v = *reinterpret_cast<const f16x8*>(&lq[(qrow + c) * 512 + (lane << 3)]);
    *reinterpret_cast<f16x8*>(&lq_s[(c << 9) + (((lane << 3)) ^ ((c & 7) << 3))]) = v;
  }
  if (tid < 32) { m_s[tid] = -__builtin_inff(); l_s[tid] = 0.f; }

  f32x4 acc[2][8] = {};
  const int r0 = ((w >> 1) & 1) << 4, c0 = (w & 1) << 4;
  __syncthreads();

  const _Float16* lkv_b = lkv + ((long)b * 8192) * 512;

  for (int it = 0; it < 256; ++it) {
    const int t0 = it << 5;
    // --- load V^T tile into regs (written to LDS after barrier)
    f16x8 rv[8];
#pragma unroll
    for (int i = 0; i < 8; ++i) {
      int ch = (w << 3) + i;                 // 0..31, 16 rows each
      int lrow = (ch << 4) + (lane >> 2);    // 0..511
      int toff = (lane & 3) << 3;
      rv[i] = *reinterpret_cast<const f16x8*>(
          &lkvT[(long)lrow * 16384 + (long)b * 8192 + t0 + toff]);
    }
    // --- S quarter = lq[16 rows] · l_kv[16 rows]^T, K=512
    f32x4 sa = {0.f, 0.f, 0.f, 0.f};
    const _Float16* kb = lkv_b + (long)(t0 + c0 + ln15) * 512 + (g << 3);
#pragma unroll
    for (int kk = 0; kk < 16; ++kk) {
      const int row = r0 + ln15;
      f16x8 a = *reinterpret_cast<const f16x8*>(
          &lq_s[row * 512 + (((kk << 5) + (g << 3)) ^ ((row & 7) << 3))]);
      f16x8 bb = *reinterpret_cast<const f16x8*>(kb + (kk << 5));
      sa = __builtin_amdgcn_mfma_f32_16x16x32_f16(a, bb, sa, 0, 0, 0);
    }
    __syncthreads();  // prev PV done with vt_s/P_s; prev softmax done with S_s
    // --- write V^T tile (row=64B, swizzle with vrow&3) and S
#pragma unroll
    for (int i = 0; i < 8; ++i) {
      int ch = (w << 3) + i;
      int vrl = (lane >> 2) & 3;
      int idx = (ch << 9) + ((lane >> 2) << 5) + ((((lane & 3) << 3)) ^ (vrl << 3));
      *reinterpret_cast<f16x8*>(&vt_s[idx]) = rv[i];
    }
    const float scale = 0.044194173824159216f;  // 1/sqrt(512)
#pragma unroll
    for (int r = 0; r < 4; ++r)
      S_s[(r0 + (g << 2) + r) * 32 + c0 + ln15] = sa[r] * scale;
    __syncthreads();
    // --- online softmax: 8 lanes per row, 4 cols each
    {
      const int row = tid >> 3, cc = (tid & 7) << 2;
      f32x4 sv = *reinterpret_cast<const f32x4*>(&S_s[(row << 5) + cc]);
      float mx = fmaxf(fmaxf(sv[0], sv[1]), fmaxf(sv[2], sv[3]));
      mx = fmaxf(mx, __shfl_xor(mx, 1));
      mx = fmaxf(mx, __shfl_xor(mx, 2));
      mx = fmaxf(mx, __shfl_xor(mx, 4));
      const float mold = m_s[row];
      const float mnew = fmaxf(mold, mx);
      float p0 = __expf(sv[0] - mnew), p1 = __expf(sv[1] - mnew);
      float p2 = __expf(sv[2] - mnew), p3 = __expf(sv[3] - mnew);
      float sum = p0 + p1 + p2 + p3;
      sum += __shfl_xor(sum, 1);
      sum += __shfl_xor(sum, 2);
      sum += __shfl_xor(sum, 4);
      if ((tid & 7) == 0) {
        const float corr = __expf(mold - mnew);
        m_s[row] = mnew;
        l_s[row] = l_s[row] * corr + sum;
        corr_s[row] = corr;
      }
      f16x4 ph = {(_Float16)p0, (_Float16)p1, (_Float16)p2, (_Float16)p3};
      *reinterpret_cast<f16x4*>(&P_s[(row << 6) + (cc ^ ((row & 7) << 3))]) = ph;
    }
    __syncthreads();
    // --- rescale + PV: ctx[32 x 512], wave owns cols [w*128, w*128+128)
    float cr0[4], cr1[4];
#pragma unroll
    for (int r = 0; r < 4; ++r) {
      cr0[r] = corr_s[(g << 2) + r];
      cr1[r] = corr_s[16 + (g << 2) + r];
    }
#pragma unroll
    for (int j = 0; j < 8; ++j)
#pragma unroll
      for (int r = 0; r < 4; ++r) {
        acc[0][j][r] *= cr0[r];
        acc[1][j][r] *= cr1[r];
      }
    f16x8 pa0 = *reinterpret_cast<const f16x8*>(
        &P_s[(ln15 << 6) + ((g << 3) ^ ((ln15 & 7) << 3))]);
    f16x8 pa1 = *reinterpret_cast<const f16x8*>(
        &P_s[((16 + ln15) << 6) + ((g << 3) ^ ((ln15 & 7) << 3))]);
#pragma unroll
    for (int j = 0; j < 8; ++j) {
      const int vrow = (w << 7) + (j << 4) + ln15;
      f16x8 vb = *reinterpret_cast<const f16x8*>(
          &vt_s[(vrow << 5) + ((g << 3) ^ ((vrow & 3) << 3))]);
      acc[0][j] = __builtin_amdgcn_mfma_f32_16x16x32_f16(pa0, vb, acc[0][j], 0, 0, 0);
      acc[1][j] = __builtin_amdgcn_mfma_f32_16x16x32_f16(pa1, vb, acc[1][j], 0, 0, 0);
    }
  }
  // --- epilogue: ctx = acc / l
  float il0[4], il1[4];
#pragma unroll
  for (int r = 0; r < 4; ++r) {
    il0[r] = 1.f / l_s[(g << 2) + r];
    il1[r] = 1.f / l_s[16 + (g << 2) + r];
  }
#pragma unroll
  for (int j = 0; j < 8; ++j) {
    const int colb = (w << 7) + (j << 4) + ln15;
#pragma unroll
    for (int r = 0; r < 4; ++r) {
      ctx[(qrow + (g << 2) + r) * 512 + colb] = (_Float16)(acc[0][j][r] * il0[r]);
      ctx[(qrow + 16 + (g << 2) + r) * 512 + colb] = (_Float16)(acc[1][j][r] * il1[r]);
    }
  }
}

// ------------------------------- launcher ----------------------------------

extern "C" void kernel_launch(void* const* d_in, const int* in_sizes, int n_in,
                              void* d_out, int out_size, void* d_ws, size_t ws_size,
                              hipStream_t stream) {
  const float* x     = (const float*)d_in[0];
  const float* cache = (const float*)d_in[1];
  const float* W_kv  = (const float*)d_in[2];
  const float* W_q   = (const float*)d_in[3];
  const float* W_lq  = (const float*)d_in[4];
  const float* W_o   = (const float*)d_in[5];

  float* out     = (float*)d_out;                 // (8192, 2048) f32
  float* lkv_out = out + (size_t)8192 * 2048;     // (2, 8192, 512) f32

  // scratch overlay in d_out's "out" region (all dead before final GEMM writes it)
  _Float16* x16    = (_Float16*)d_out;            // 16,777,216 elems
  _Float16* lq16   = x16 + 16777216;              //  4,194,304
  _Float16* Wq16   = lq16 + 4194304;              //  4,194,304  (W_q original (d,e) layout)
  _Float16* WlqT   = Wq16 + 4194304;              //  1,048,576
  _Float16* WcombT = WlqT + 1048576;              //  1,048,576
  _Float16* WkvT   = WcombT + 1048576;            //  1,048,576  (56.6MB <= 67.1MB)

  // ws: buffers that must survive into the final GEMM / attention (44.0 MB)
  _Float16* lkv16 = (_Float16*)d_ws;              //  8,388,608
  _Float16* lkvT  = lkv16 + 8388608;              //  8,388,608
  _Float16* ctx   = lkvT + 8388608;               //  4,194,304
  _Float16* WoT   = ctx + 4194304;                //  1,048,576

  // converts / transposes
  k_cvt<<<1024, 256, 0, stream>>>(x, x16, 16777216 / 4);
  k_cache<<<1024, 256, 0, stream>>>(cache, lkv_out, lkv16, 4194304 / 4);
  k_tc<<<dim3(16, 64), 256, 0, stream>>>(W_kv, WkvT, 2048, 512);
  k_cvt<<<1024, 256, 0, stream>>>(W_q, Wq16, 4194304 / 4);   // NO transpose: GEMM needs B[d][e]=W_q[d][e]
  k_tc<<<dim3(16, 64), 256, 0, stream>>>(W_lq, WlqT, 2048, 512);
  k_tc<<<dim3(64, 16), 256, 0, stream>>>(W_o, WoT, 512, 2048);

  // l_kv_new = x @ W_kv  -> f32 l_kv rows + fp16 copy (row remap)
  k_gemm<2><<<dim3(64, 4), 256, 0, stream>>>(x16, WkvT, lkv_out, lkv16, 8192, 512, 2048);
  // W_comb^T[l][d] = sum_e WlqT[l][e] * Wq16[d][e]  (= W_lq[e][l] * W_q[d][e])
  k_gemm<1><<<dim3(4, 16), 256, 0, stream>>>(WlqT, Wq16, nullptr, WcombT, 512, 2048, 2048);
  // lq = x @ W_comb
  k_gemm<1><<<dim3(64, 4), 256, 0, stream>>>(x16, WcombT, nullptr, lq16, 8192, 512, 2048);
  // l_kv^T for the PV operand
  k_tb<<<dim3(16, 512), 256, 0, stream>>>(lkv16, lkvT, 16384, 512);
  // flash attention in latent space
  k_attn<<<dim3(128, 2), 256, 0, stream>>>(lq16, lkv16, lkvT, ctx);
  // out = ctx @ W_o
  k_gemm<0><<<dim3(64, 16), 256, 0, stream>>>(ctx, WoT, out, nullptr, 8192, 2048, 512);
}